// Round 1
// baseline (1635.942 us; speedup 1.0000x reference)
//
#include <hip/hip_runtime.h>

// Problem constants (match reference)
#define N_NODES_C 100000
#define N_EDGES_C 500000
#define NUM_REL_C 1000
#define E_HID_C   256      // x_e hidden
// T_HID=128, R_HID=128 hard-coded as 128 below

// Segment-sum kernel geometry
#define CCH       16                       // edge chunks (replicas)
#define CHUNK_LEN (N_EDGES_C / CCH)        // 31250
#define NGRP      16                       // relation groups of 64
#define GRP_RELS  64
#define RELS_PAD  1024                     // NGRP*GRP_RELS, >= NUM_REL

// ---------------------------------------------------------------------------
// K1: per-relation segment sums of gathered x_e rows (head and tail), plus
// per-relation edge counts. Grid = CCH * 2 * NGRP blocks of 1024 threads.
// Block (c, which, g): scans edge chunk c, accumulates edges whose rel is in
// group g into a 64x256 LDS table (which=0: src rows, which=1: dst rows),
// then writes its table slice to replica c (full coverage -> no pre-zeroing,
// no global atomics).
// ---------------------------------------------------------------------------
__global__ __launch_bounds__(1024)
void k_segsum(const float* __restrict__ x_e,
              const int* __restrict__ edge_index,
              const int* __restrict__ rel,
              float* __restrict__ repl,      // [CCH][2][RELS_PAD][E_HID]
              int* __restrict__ cntRepl)     // [CCH][RELS_PAD]
{
    __shared__ float acc[GRP_RELS * E_HID_C];   // 64 KiB
    __shared__ int scnt[GRP_RELS];

    const int bx    = blockIdx.x;
    const int c     = bx >> 5;
    const int sub   = bx & 31;
    const int which = sub >> 4;   // 0 = head(src), 1 = tail(dst)
    const int g     = sub & 15;
    const int tid   = threadIdx.x;

    for (int i = tid; i < GRP_RELS * E_HID_C; i += 1024) acc[i] = 0.0f;
    if (tid < GRP_RELS) scnt[tid] = 0;
    __syncthreads();

    const int lane = tid & 63;
    const int wv   = tid >> 6;
    const int chunkStart = c * CHUNK_LEN;
    const int* __restrict__ nodes = edge_index + (size_t)which * N_EDGES_C;
    const int ntiles = (CHUNK_LEN + 63) >> 6;

    for (int t = wv; t < ntiles; t += 16) {
        const int off   = t * 64 + lane;
        const bool valid = off < CHUNK_LEN;
        const int e  = chunkStart + (valid ? off : 0);
        const int r  = valid ? rel[e] : -1;
        const int nd = valid ? nodes[e] : 0;
        const bool match = valid && ((r >> 6) == g);
        if (which == 0 && match) atomicAdd(&scnt[r & 63], 1);
        unsigned long long mask = __ballot(match);
        while (mask) {
            const int j = __builtin_ctzll(mask);
            mask &= mask - 1;
            const int rl = __shfl(r, j) & 63;
            const int n  = __shfl(nd, j);
            const float* __restrict__ row = x_e + (size_t)n * E_HID_C;
            // strided lane ownership: lane l owns elems l, l+64, l+128, l+192
            // -> LDS bank (l % 32): 2 lanes/bank = conflict-free
            const float v0 = row[lane];
            const float v1 = row[lane + 64];
            const float v2 = row[lane + 128];
            const float v3 = row[lane + 192];
            atomicAdd(&acc[rl * E_HID_C + lane], v0);
            atomicAdd(&acc[rl * E_HID_C + lane + 64], v1);
            atomicAdd(&acc[rl * E_HID_C + lane + 128], v2);
            atomicAdd(&acc[rl * E_HID_C + lane + 192], v3);
        }
    }
    __syncthreads();

    float* __restrict__ dst =
        repl + ((((size_t)c * 2 + which) * RELS_PAD) + (size_t)g * GRP_RELS) * E_HID_C;
    for (int i = tid; i < GRP_RELS * E_HID_C; i += 1024) dst[i] = acc[i];
    if (which == 0 && tid < GRP_RELS)
        cntRepl[c * RELS_PAD + g * GRP_RELS + tid] = scnt[tid];
}

// ---------------------------------------------------------------------------
// K2: reduce replicas -> per-rel means in x_e space -> project with W_tc1 to
// get (mean_h, mean_t) in t-space -> rin row [256] -> project with W_sr1 to
// get x_res2_rel (= x_type) row [128]. Grid = NUM_REL blocks of 256 threads.
// ---------------------------------------------------------------------------
__global__ __launch_bounds__(256)
void k_tables(const float* __restrict__ repl,
              const int* __restrict__ cntRepl,
              const float* __restrict__ W_tc1, const float* __restrict__ b_tc1,
              const float* __restrict__ W_sr1, const float* __restrict__ b_sr1,
              float* __restrict__ rin_t,   // [NUM_REL][256]
              float* __restrict__ xt_t)    // [NUM_REL][128]
{
    __shared__ float sh[E_HID_C], st[E_HID_C], rin[E_HID_C];
    const int r = blockIdx.x;
    const int d = threadIdx.x;

    float s0 = 0.0f, s1 = 0.0f;
    for (int c = 0; c < CCH; ++c) {
        s0 += repl[(((size_t)c * 2 + 0) * RELS_PAD + r) * E_HID_C + d];
        s1 += repl[(((size_t)c * 2 + 1) * RELS_PAD + r) * E_HID_C + d];
    }
    int cnt = 0;
    for (int c = 0; c < CCH; ++c) cnt += cntRepl[c * RELS_PAD + r];
    const float inv = 1.0f / (float)(cnt > 0 ? cnt : 1);
    sh[d] = s0 * inv;
    st[d] = s1 * inv;
    __syncthreads();

    // t_c1 projection: threads 0..127 -> mean_h @ W_tc1, 128..255 -> mean_t
    {
        const int j = d & 127;
        const float* __restrict__ src = (d < 128) ? sh : st;
        float a = b_tc1[j];
        for (int k = 0; k < E_HID_C; ++k)
            a += src[k] * W_tc1[k * 128 + j];
        rin[(d < 128 ? 0 : 128) + j] = a;   // concat(mean_h, mean_t)
    }
    __syncthreads();

    rin_t[(size_t)r * E_HID_C + d] = rin[d];
    if (d < 128) {
        float a = b_sr1[d];
        for (int k = 0; k < E_HID_C; ++k)
            a += rin[k] * W_sr1[k * 128 + d];
        xt_t[(size_t)r * 128 + d] = a;      // x_res2_rel == x_type (nonempty)
    }
}

// ---------------------------------------------------------------------------
// K3: streaming output. out[e] = [ x_res1[e] + xt[rel[e]] | rin[rel[e]] ]
// One float4 per thread-iteration; 96 float4 per edge row.
// ---------------------------------------------------------------------------
__global__ __launch_bounds__(256)
void k_out(const float* __restrict__ x_res1,
           const int* __restrict__ rel,
           const float* __restrict__ rin_t,
           const float* __restrict__ xt_t,
           float4* __restrict__ out)
{
    const unsigned total = (unsigned)N_EDGES_C * 96u;   // 48M float4
    const float4* __restrict__ xr4  = (const float4*)x_res1;
    const float4* __restrict__ rin4 = (const float4*)rin_t;
    const float4* __restrict__ xt4  = (const float4*)xt_t;
    for (unsigned idx = blockIdx.x * 256u + threadIdx.x; idx < total;
         idx += gridDim.x * 256u) {
        const unsigned e = idx / 96u;
        const unsigned j = idx - e * 96u;
        const int r = rel[e];
        float4 o;
        if (j < 32u) {
            const float4 a = xr4[(size_t)e * 32 + j];
            const float4 b = xt4[(size_t)r * 32 + j];
            o.x = a.x + b.x; o.y = a.y + b.y; o.z = a.z + b.z; o.w = a.w + b.w;
        } else {
            o = rin4[(size_t)r * 64 + (j - 32u)];
        }
        out[idx] = o;
    }
}

// ---------------------------------------------------------------------------
extern "C" void kernel_launch(void* const* d_in, const int* in_sizes, int n_in,
                              void* d_out, int out_size, void* d_ws, size_t ws_size,
                              hipStream_t stream)
{
    const float* x_e    = (const float*)d_in[0];
    const float* x_res1 = (const float*)d_in[1];
    const float* W_tc1  = (const float*)d_in[2];
    const float* b_tc1  = (const float*)d_in[3];
    const float* W_sr1  = (const float*)d_in[4];
    const float* b_sr1  = (const float*)d_in[5];
    // d_in[6] = a1, d_in[7] = a5: UNUSED — the scatter-softmax cancels:
    // x_type[r] = (sum of alpha in segment r) * x_res2_rel[r] = x_res2_rel[r].
    const int* edge_index = (const int*)d_in[8];
    const int* rel        = (const int*)d_in[9];
    // d_in[10] = rel_size = arange(E): x_res2[rel_size] == x_res2, unused.

    char* ws = (char*)d_ws;
    float* repl  = (float*)(ws);                 // 16*2*1024*256*4 = 33,554,432 B
    int*   cntR  = (int*)  (ws + 33554432);      // 16*1024*4       =     65,536 B
    float* rin_t = (float*)(ws + 33619968);      // 1024*256*4      =  1,048,576 B
    float* xt_t  = (float*)(ws + 34668544);      // 1024*128*4      =    524,288 B
    // total ws use: 35,192,832 B

    k_segsum<<<CCH * 2 * NGRP, 1024, 0, stream>>>(x_e, edge_index, rel, repl, cntR);
    k_tables<<<NUM_REL_C, 256, 0, stream>>>(repl, cntR, W_tc1, b_tc1,
                                            W_sr1, b_sr1, rin_t, xt_t);
    k_out<<<2048, 256, 0, stream>>>(x_res1, rel, rin_t, xt_t, (float4*)d_out);
}

// Round 2
// 629.077 us; speedup vs baseline: 2.6005x; 2.6005x over previous
//
#include <hip/hip_runtime.h>

// Problem constants (match reference)
#define N_NODES_C 100000
#define N_EDGES_C 500000
#define NUM_REL_C 1000
#define E_HID_C   256
#define RPAD      1024   // padded relation count (power of 2 for the scan)

// ---------------------------------------------------------------------------
// Pipeline:
//   k_zero    : zero the relation histogram
//   k_hist    : hist[r] = edge count per relation (global int atomics)
//   k_scan    : exclusive prefix sum -> start[], cursor[]
//   k_scatter : bucket src/dst node ids by relation (atomic cursor)
//   k_accum   : per-rel register-accumulated segment sums of x_e rows
//               (NO atomics in the hot loop; one dwordx4 gather per edge/wave)
//   k_tables  : means -> t_c1 projection -> rin row -> s_r1 projection -> xt
//   k_out     : streaming output assembly
// Softmax/attention cancel algebraically (sum of alpha over a segment = 1),
// and t_c1 is linear so it commutes with the per-rel mean: only per-rel means
// of raw x_e rows are needed.
// ---------------------------------------------------------------------------

__global__ __launch_bounds__(1024)
void k_zero(int* __restrict__ hist) {
    hist[threadIdx.x] = 0;
}

__global__ __launch_bounds__(256)
void k_hist(const int* __restrict__ rel, int* __restrict__ hist) {
    const int stride = gridDim.x * 256;
    for (int e = blockIdx.x * 256 + threadIdx.x; e < N_EDGES_C; e += stride)
        atomicAdd(&hist[rel[e]], 1);
}

__global__ __launch_bounds__(1024)
void k_scan(const int* __restrict__ hist,
            int* __restrict__ startc, int* __restrict__ cursor) {
    __shared__ int s[2][RPAD];
    const int t = threadIdx.x;
    const int v = hist[t];          // t < RPAD; hist zero-padded past NUM_REL
    s[0][t] = v;
    __syncthreads();
    int cur = 0;
    for (int off = 1; off < RPAD; off <<= 1) {
        const int add = (t >= off) ? s[cur][t - off] : 0;
        s[cur ^ 1][t] = s[cur][t] + add;
        cur ^= 1;
        __syncthreads();
    }
    const int excl = s[cur][t] - v;
    startc[t] = excl;
    cursor[t] = excl;
}

__global__ __launch_bounds__(256)
void k_scatter(const int* __restrict__ edge_index, const int* __restrict__ rel,
               int* __restrict__ cursor,
               int* __restrict__ bsrc, int* __restrict__ bdst) {
    const int stride = gridDim.x * 256;
    for (int e = blockIdx.x * 256 + threadIdx.x; e < N_EDGES_C; e += stride) {
        const int r = rel[e];
        const int s = edge_index[e];
        const int d = edge_index[N_EDGES_C + e];
        const int pos = atomicAdd(&cursor[r], 1);
        bsrc[pos] = s;
        bdst[pos] = d;
    }
}

// One block per relation: waves 0-3 accumulate head (src) quarters, waves 4-7
// tail (dst) quarters, each into 4 accumulator VGPRs (float4). One
// global_load_dwordx4 per edge per wave gathers the full 1KB x_e row.
// Non-atomic LDS tree reduce at the end.
__global__ __launch_bounds__(512)
void k_accum(const float* __restrict__ x_e,
             const int* __restrict__ bsrc, const int* __restrict__ bdst,
             const int* __restrict__ startc, const int* __restrict__ hist,
             float* __restrict__ sums)      // [NUM_REL][2][E_HID]
{
    __shared__ float red[8][E_HID_C];       // 8 KiB
    const int r    = blockIdx.x;
    const int tid  = threadIdx.x;
    const int w    = tid >> 6;
    const int lane = tid & 63;
    const int which = w >> 2;               // 0 = head, 1 = tail
    const int q     = w & 3;                // edge quarter
    const int base = startc[r];
    const int cnt  = hist[r];
    const int qlen = (cnt + 3) >> 2;
    const int lo = base + q * qlen;
    const int hi = min(base + cnt, lo + qlen);
    const int* __restrict__ bn = which ? bdst : bsrc;

    float4 a = make_float4(0.f, 0.f, 0.f, 0.f);
    // 2-deep prefetch of the (wave-uniform) node index hides the scalar-load
    // latency so the row gathers of iteration i+1 can issue during i.
    int n0 = (lo     < hi) ? bn[lo]     : 0;
    int n1 = (lo + 1 < hi) ? bn[lo + 1] : 0;
#pragma unroll 2
    for (int i = lo; i < hi; ++i) {
        const float4* __restrict__ row4 =
            (const float4*)(x_e + (size_t)n0 * E_HID_C);
        const float4 v = row4[lane];        // 64 lanes x 16B = full row
        n0 = n1;
        n1 = (i + 2 < hi) ? bn[i + 2] : 0;
        a.x += v.x; a.y += v.y; a.z += v.z; a.w += v.w;
    }

    ((float4*)&red[w][0])[lane] = a;        // red[w][4*lane .. 4*lane+3]
    __syncthreads();

    const int wh = tid >> 8;                // 0 = head, 1 = tail
    const int d  = tid & 255;
    const float s = red[wh * 4 + 0][d] + red[wh * 4 + 1][d] +
                    red[wh * 4 + 2][d] + red[wh * 4 + 3][d];
    sums[((size_t)r * 2 + wh) * E_HID_C + d] = s;
}

// Per-rel means -> project with W_tc1 -> rin row [256] -> project with W_sr1
// -> xt row [128] (= x_res2_rel = x_type for nonempty segments).
__global__ __launch_bounds__(256)
void k_tables(const float* __restrict__ sums, const int* __restrict__ hist,
              const float* __restrict__ W_tc1, const float* __restrict__ b_tc1,
              const float* __restrict__ W_sr1, const float* __restrict__ b_sr1,
              float* __restrict__ rin_t,   // [NUM_REL][256]
              float* __restrict__ xt_t)    // [NUM_REL][128]
{
    __shared__ float sh[E_HID_C], st[E_HID_C], rin[E_HID_C];
    const int r = blockIdx.x;
    const int d = threadIdx.x;

    const int cnt = hist[r];
    const float inv = 1.0f / (float)(cnt > 0 ? cnt : 1);
    sh[d] = sums[((size_t)r * 2 + 0) * E_HID_C + d] * inv;
    st[d] = sums[((size_t)r * 2 + 1) * E_HID_C + d] * inv;
    __syncthreads();

    {
        const int j = d & 127;
        const float* __restrict__ src = (d < 128) ? sh : st;
        float acc = b_tc1[j];
        for (int k = 0; k < E_HID_C; ++k)
            acc += src[k] * W_tc1[k * 128 + j];
        rin[(d < 128 ? 0 : 128) + j] = acc;   // concat(mean_h, mean_t)
    }
    __syncthreads();

    rin_t[(size_t)r * E_HID_C + d] = rin[d];
    if (d < 128) {
        float acc = b_sr1[d];
        for (int k = 0; k < E_HID_C; ++k)
            acc += rin[k] * W_sr1[k * 128 + d];
        xt_t[(size_t)r * 128 + d] = acc;
    }
}

// out[e] = [ x_res1[e] + xt[rel[e]] | rin[rel[e]] ]   (96 float4 per edge)
__global__ __launch_bounds__(256)
void k_out(const float* __restrict__ x_res1,
           const int* __restrict__ rel,
           const float* __restrict__ rin_t,
           const float* __restrict__ xt_t,
           float4* __restrict__ out)
{
    const unsigned total = (unsigned)N_EDGES_C * 96u;
    const float4* __restrict__ xr4  = (const float4*)x_res1;
    const float4* __restrict__ rin4 = (const float4*)rin_t;
    const float4* __restrict__ xt4  = (const float4*)xt_t;
    for (unsigned idx = blockIdx.x * 256u + threadIdx.x; idx < total;
         idx += gridDim.x * 256u) {
        const unsigned e = idx / 96u;
        const unsigned j = idx - e * 96u;
        const int r = rel[e];
        float4 o;
        if (j < 32u) {
            const float4 a = xr4[(size_t)e * 32 + j];
            const float4 b = xt4[(size_t)r * 32 + j];
            o.x = a.x + b.x; o.y = a.y + b.y; o.z = a.z + b.z; o.w = a.w + b.w;
        } else {
            o = rin4[(size_t)r * 64 + (j - 32u)];
        }
        out[idx] = o;
    }
}

// ---------------------------------------------------------------------------
extern "C" void kernel_launch(void* const* d_in, const int* in_sizes, int n_in,
                              void* d_out, int out_size, void* d_ws, size_t ws_size,
                              hipStream_t stream)
{
    const float* x_e    = (const float*)d_in[0];
    const float* x_res1 = (const float*)d_in[1];
    const float* W_tc1  = (const float*)d_in[2];
    const float* b_tc1  = (const float*)d_in[3];
    const float* W_sr1  = (const float*)d_in[4];
    const float* b_sr1  = (const float*)d_in[5];
    // d_in[6]=a1, d_in[7]=a5 unused: scatter-softmax cancels (sum alpha = 1).
    const int* edge_index = (const int*)d_in[8];
    const int* rel        = (const int*)d_in[9];
    // d_in[10] = rel_size = arange(E): identity gather, unused.

    char* ws = (char*)d_ws;
    int*   hist   = (int*)  (ws);                  //  4,096 B  [RPAD]
    int*   startc = (int*)  (ws + 4096);           //  4,096 B  [RPAD]
    int*   cursor = (int*)  (ws + 8192);           //  4,096 B  [RPAD]
    int*   bsrc   = (int*)  (ws + 12288);          //  2,000,000 B
    int*   bdst   = (int*)  (ws + 2012288);        //  2,000,000 B
    float* sums   = (float*)(ws + 4012288);        //  2,048,000 B
    float* rin_t  = (float*)(ws + 6060288);        //  1,024,000 B
    float* xt_t   = (float*)(ws + 7084288);        //    512,000 B
    // total ws use: 7,596,288 B

    k_zero   <<<1, RPAD, 0, stream>>>(hist);
    k_hist   <<<1024, 256, 0, stream>>>(rel, hist);
    k_scan   <<<1, RPAD, 0, stream>>>(hist, startc, cursor);
    k_scatter<<<1024, 256, 0, stream>>>(edge_index, rel, cursor, bsrc, bdst);
    k_accum  <<<NUM_REL_C, 512, 0, stream>>>(x_e, bsrc, bdst, startc, hist, sums);
    k_tables <<<NUM_REL_C, 256, 0, stream>>>(sums, hist, W_tc1, b_tc1,
                                             W_sr1, b_sr1, rin_t, xt_t);
    k_out    <<<2048, 256, 0, stream>>>(x_res1, rel, rin_t, xt_t, (float4*)d_out);
}

// Round 3
// 404.873 us; speedup vs baseline: 4.0406x; 1.5538x over previous
//
#include <hip/hip_runtime.h>

// Problem constants (match reference)
#define N_NODES_C 100000
#define N_EDGES_C 500000
#define NUM_REL_C 1000
#define E_HID_C   256
#define RPAD      1024   // padded relation count (power of 2 for the scan)

#define NB_SORT   125    // sort blocks; 500000/125 = 4000 edges per block
#define CHUNK_E   (N_EDGES_C / NB_SORT)

// ---------------------------------------------------------------------------
// Algebra (validated in R1/R2): the scatter-softmax cancels (sum of alpha over
// a segment is 1, so x_type[r] = x_res2_rel[r]); t_c1 is linear so it commutes
// with the per-rel mean. Only per-rel means of raw x_e rows are needed.
//
// Pipeline (all atomic-free on global memory):
//   k_hist    : per-block LDS histograms -> part[b][r]
//   k_scan    : cnt[r], exclusive start[r], per-block bases pbase[b][r]
//   k_scatter : bucket src/dst node ids by relation via LDS cursors
//   k_accum   : per-rel register-accumulated segment sums (8 gathers in flight)
//   k_tables  : means -> t_c1 proj -> rin row[256] -> s_r1 proj -> xt row[128]
//   k_out     : streaming output assembly (division-free)
// ---------------------------------------------------------------------------

__global__ __launch_bounds__(1024)
void k_hist(const int* __restrict__ rel, int* __restrict__ part) {
    __shared__ int h[RPAD];
    const int b = blockIdx.x, tid = threadIdx.x;
    h[tid] = 0;
    __syncthreads();
    const int base = b * CHUNK_E;
    for (int e = base + tid; e < base + CHUNK_E; e += 1024)
        atomicAdd(&h[rel[e]], 1);
    __syncthreads();
    part[b * RPAD + tid] = h[tid];
}

__global__ __launch_bounds__(1024)
void k_scan(const int* __restrict__ part,
            int* __restrict__ cnt, int* __restrict__ startc,
            int* __restrict__ pbase) {
    __shared__ int s[2][RPAD];
    const int t = threadIdx.x;
    int c = 0;
    for (int b = 0; b < NB_SORT; ++b) c += part[b * RPAD + t];
    s[0][t] = c;
    __syncthreads();
    int cur = 0;
    for (int off = 1; off < RPAD; off <<= 1) {
        const int add = (t >= off) ? s[cur][t - off] : 0;
        s[cur ^ 1][t] = s[cur][t] + add;
        cur ^= 1;
        __syncthreads();
    }
    const int excl = s[cur][t] - c;
    cnt[t] = c;
    startc[t] = excl;
    int run = excl;
    for (int b = 0; b < NB_SORT; ++b) {
        pbase[b * RPAD + t] = run;
        run += part[b * RPAD + t];
    }
}

__global__ __launch_bounds__(1024)
void k_scatter(const int* __restrict__ edge_index, const int* __restrict__ rel,
               const int* __restrict__ pbase,
               int* __restrict__ bsrc, int* __restrict__ bdst) {
    __shared__ int cur[RPAD];
    const int b = blockIdx.x, tid = threadIdx.x;
    cur[tid] = pbase[b * RPAD + tid];
    __syncthreads();
    const int base = b * CHUNK_E;
    for (int e = base + tid; e < base + CHUNK_E; e += 1024) {
        const int r = rel[e];
        const int pos = atomicAdd(&cur[r], 1);   // LDS atomic, returns old
        bsrc[pos] = edge_index[e];
        bdst[pos] = edge_index[N_EDGES_C + e];
    }
}

// One block per relation: waves 0-3 accumulate head (src) quarters, waves 4-7
// tail (dst). 64 edge indices are loaded per wave in ONE coalesced load and
// shfl-broadcast; row gathers issue 8-deep for memory-level parallelism.
__global__ __launch_bounds__(512)
void k_accum(const float* __restrict__ x_e,
             const int* __restrict__ bsrc, const int* __restrict__ bdst,
             const int* __restrict__ startc, const int* __restrict__ cnt,
             float* __restrict__ sums)      // [NUM_REL][2][E_HID]
{
    __shared__ float red[8][E_HID_C];       // 8 KiB
    const int r    = blockIdx.x;
    const int tid  = threadIdx.x;
    const int w    = tid >> 6;
    const int lane = tid & 63;
    const int which = w >> 2;               // 0 = head, 1 = tail
    const int q     = w & 3;                // edge quarter
    const int base = startc[r];
    const int c    = cnt[r];
    const int qlen = (c + 3) >> 2;
    const int lo = base + q * qlen;
    const int hi = min(base + c, lo + qlen);
    const int* __restrict__ bn = which ? bdst : bsrc;

    float4 a = make_float4(0.f, 0.f, 0.f, 0.f);
    for (int g = lo; g < hi; g += 64) {
        const int m = min(64, hi - g);
        const int myidx = (g + lane < hi) ? bn[g + lane] : 0;
        int k = 0;
        for (; k + 8 <= m; k += 8) {
            float4 v[8];
#pragma unroll
            for (int u = 0; u < 8; ++u) {
                const int n = __shfl(myidx, k + u);
                v[u] = ((const float4*)(x_e + (size_t)n * E_HID_C))[lane];
            }
#pragma unroll
            for (int u = 0; u < 8; ++u) {
                a.x += v[u].x; a.y += v[u].y; a.z += v[u].z; a.w += v[u].w;
            }
        }
        for (; k < m; ++k) {
            const int n = __shfl(myidx, k);
            const float4 v = ((const float4*)(x_e + (size_t)n * E_HID_C))[lane];
            a.x += v.x; a.y += v.y; a.z += v.z; a.w += v.w;
        }
    }

    ((float4*)&red[w][0])[lane] = a;
    __syncthreads();

    const int wh = tid >> 8;                // 0 = head, 1 = tail
    const int d  = tid & 255;
    const float s = red[wh * 4 + 0][d] + red[wh * 4 + 1][d] +
                    red[wh * 4 + 2][d] + red[wh * 4 + 3][d];
    sums[((size_t)r * 2 + wh) * E_HID_C + d] = s;
}

// Per-rel means -> project with W_tc1 -> rin row [256] -> project with W_sr1
// -> xt row [128] (= x_res2_rel = x_type for nonempty segments).
__global__ __launch_bounds__(256)
void k_tables(const float* __restrict__ sums, const int* __restrict__ cnt,
              const float* __restrict__ W_tc1, const float* __restrict__ b_tc1,
              const float* __restrict__ W_sr1, const float* __restrict__ b_sr1,
              float* __restrict__ rin_t,   // [NUM_REL][256]
              float* __restrict__ xt_t)    // [NUM_REL][128]
{
    __shared__ float sh[E_HID_C], st[E_HID_C], rin[E_HID_C];
    const int r = blockIdx.x;
    const int d = threadIdx.x;

    const int c = cnt[r];
    const float inv = 1.0f / (float)(c > 0 ? c : 1);
    sh[d] = sums[((size_t)r * 2 + 0) * E_HID_C + d] * inv;
    st[d] = sums[((size_t)r * 2 + 1) * E_HID_C + d] * inv;
    __syncthreads();

    {
        const int j = d & 127;
        const float* __restrict__ src = (d < 128) ? sh : st;
        float acc = b_tc1[j];
        for (int k = 0; k < E_HID_C; ++k)
            acc += src[k] * W_tc1[k * 128 + j];
        rin[(d < 128 ? 0 : 128) + j] = acc;   // concat(mean_h, mean_t)
    }
    __syncthreads();

    rin_t[(size_t)r * E_HID_C + d] = rin[d];
    if (d < 128) {
        float acc = b_sr1[d];
        for (int k = 0; k < E_HID_C; ++k)
            acc += rin[k] * W_sr1[k * 128 + d];
        xt_t[(size_t)r * 128 + d] = acc;
    }
}

// out[e] = [ x_res1[e] + xt[rel[e]] | rin[rel[e]] ]. 8 edges per block; each
// 32-lane group owns one edge: 4 float4 loads + 3 float4 stores per thread,
// no integer division.
__global__ __launch_bounds__(256)
void k_out(const float* __restrict__ x_res1,
           const int* __restrict__ rel,
           const float* __restrict__ rin_t,
           const float* __restrict__ xt_t,
           float4* __restrict__ out)
{
    const float4* __restrict__ xr4  = (const float4*)x_res1;
    const float4* __restrict__ rin4 = (const float4*)rin_t;
    const float4* __restrict__ xt4  = (const float4*)xt_t;
    const int tid = threadIdx.x;
    const unsigned jj = tid & 31;
    const unsigned e  = blockIdx.x * 8u + (tid >> 5);
    const int r = rel[e];
    const float4 a = xr4[(size_t)e * 32 + jj];
    const float4 t = xt4[(size_t)r * 32 + jj];
    float4 o;
    o.x = a.x + t.x; o.y = a.y + t.y; o.z = a.z + t.z; o.w = a.w + t.w;
    float4* __restrict__ dst = out + (size_t)e * 96;
    dst[jj]      = o;
    dst[32 + jj] = rin4[(size_t)r * 64 + jj];
    dst[64 + jj] = rin4[(size_t)r * 64 + 32 + jj];
}

// ---------------------------------------------------------------------------
extern "C" void kernel_launch(void* const* d_in, const int* in_sizes, int n_in,
                              void* d_out, int out_size, void* d_ws, size_t ws_size,
                              hipStream_t stream)
{
    const float* x_e    = (const float*)d_in[0];
    const float* x_res1 = (const float*)d_in[1];
    const float* W_tc1  = (const float*)d_in[2];
    const float* b_tc1  = (const float*)d_in[3];
    const float* W_sr1  = (const float*)d_in[4];
    const float* b_sr1  = (const float*)d_in[5];
    // d_in[6]=a1, d_in[7]=a5 unused: scatter-softmax cancels (sum alpha = 1).
    const int* edge_index = (const int*)d_in[8];
    const int* rel        = (const int*)d_in[9];
    // d_in[10] = rel_size = arange(E): identity gather, unused.

    char* ws = (char*)d_ws;
    int*   part   = (int*)  (ws);                  // 125*1024*4 = 512,000 B
    int*   pbase  = (int*)  (ws + 512000);         // 512,000 B
    int*   cnt    = (int*)  (ws + 1024000);        // 4,096 B
    int*   startc = (int*)  (ws + 1028096);        // 4,096 B
    int*   bsrc   = (int*)  (ws + 1032192);        // 2,000,000 B
    int*   bdst   = (int*)  (ws + 3032192);        // 2,000,000 B
    float* sums   = (float*)(ws + 5032192);        // 2,048,000 B
    float* rin_t  = (float*)(ws + 7080192);        // 1,024,000 B
    float* xt_t   = (float*)(ws + 8104192);        // 512,000 B
    // total ws use: 8,616,192 B

    k_hist   <<<NB_SORT, 1024, 0, stream>>>(rel, part);
    k_scan   <<<1, RPAD, 0, stream>>>(part, cnt, startc, pbase);
    k_scatter<<<NB_SORT, 1024, 0, stream>>>(edge_index, rel, pbase, bsrc, bdst);
    k_accum  <<<NUM_REL_C, 512, 0, stream>>>(x_e, bsrc, bdst, startc, cnt, sums);
    k_tables <<<NUM_REL_C, 256, 0, stream>>>(sums, cnt, W_tc1, b_tc1,
                                             W_sr1, b_sr1, rin_t, xt_t);
    k_out    <<<N_EDGES_C / 8, 256, 0, stream>>>(x_res1, rel, rin_t, xt_t,
                                                 (float4*)d_out);
}

// Round 4
// 381.762 us; speedup vs baseline: 4.2852x; 1.0605x over previous
//
#include <hip/hip_runtime.h>

// Problem constants (match reference)
#define N_NODES_C 100000
#define N_EDGES_C 500000
#define NUM_REL_C 1000
#define E_HID_C   256
#define RPAD      1024   // padded relation count (power of 2 for the scan)

#define NB_SORT   125    // sort blocks; 500000/125 = 4000 edges per block
#define CHUNK_E   (N_EDGES_C / NB_SORT)

// ---------------------------------------------------------------------------
// Algebra (validated R1-R3): scatter-softmax cancels (sum of alpha over each
// segment is 1 -> x_type[r] = x_res2_rel[r]); t_c1 is linear so it commutes
// with the per-rel mean. Only per-rel means of raw x_e rows are needed.
//
// Pipeline (no global atomics on the hot paths):
//   k_zero    : cnt[] = 0
//   k_hist    : per-block LDS histograms -> part[b][r]; atomic cnt[r]
//   k_scan    : exclusive prefix sum cnt -> startc (1024-wide, ~3 us)
//   k_pbase   : per-block bases pbase[b][r] (1024 parallel rel-threads)
//   k_scatter : bucket src/dst node ids by relation via LDS cursors
//   k_accum   : per-rel register-accumulated segment sums (8 gathers in
//               flight) FUSED with means + both projections -> rin_t, xt_t
//   k_out     : streaming output assembly (division-free)
// ---------------------------------------------------------------------------

__global__ __launch_bounds__(1024)
void k_zero(int* __restrict__ cnt) {
    cnt[threadIdx.x] = 0;
}

__global__ __launch_bounds__(1024)
void k_hist(const int* __restrict__ rel, int* __restrict__ part,
            int* __restrict__ cnt) {
    __shared__ int h[RPAD];
    const int b = blockIdx.x, tid = threadIdx.x;
    h[tid] = 0;
    __syncthreads();
    const int base = b * CHUNK_E;
    for (int e = base + tid; e < base + CHUNK_E; e += 1024)
        atomicAdd(&h[rel[e]], 1);
    __syncthreads();
    const int v = h[tid];
    part[b * RPAD + tid] = v;
    if (v) atomicAdd(&cnt[tid], v);
}

__global__ __launch_bounds__(1024)
void k_scan(const int* __restrict__ cnt, int* __restrict__ startc) {
    __shared__ int s[2][RPAD];
    const int t = threadIdx.x;
    const int v = cnt[t];
    s[0][t] = v;
    __syncthreads();
    int cur = 0;
    for (int off = 1; off < RPAD; off <<= 1) {
        const int add = (t >= off) ? s[cur][t - off] : 0;
        s[cur ^ 1][t] = s[cur][t] + add;
        cur ^= 1;
        __syncthreads();
    }
    startc[t] = s[cur][t] - v;
}

// pbase[b][r] = startc[r] + sum_{b'<b} part[b'][r]; 1024 rel-threads in
// parallel (16 blocks x 64), serial only over the 125 sort blocks.
__global__ __launch_bounds__(64)
void k_pbase(const int* __restrict__ part, const int* __restrict__ startc,
             int* __restrict__ pbase) {
    const int r = blockIdx.x * 64 + threadIdx.x;   // r < RPAD
    int run = startc[r];
#pragma unroll 5
    for (int b = 0; b < NB_SORT; ++b) {
        pbase[b * RPAD + r] = run;
        run += part[b * RPAD + r];
    }
}

__global__ __launch_bounds__(1024)
void k_scatter(const int* __restrict__ edge_index, const int* __restrict__ rel,
               const int* __restrict__ pbase,
               int* __restrict__ bsrc, int* __restrict__ bdst) {
    __shared__ int cur[RPAD];
    const int b = blockIdx.x, tid = threadIdx.x;
    cur[tid] = pbase[b * RPAD + tid];
    __syncthreads();
    const int base = b * CHUNK_E;
    for (int e = base + tid; e < base + CHUNK_E; e += 1024) {
        const int r = rel[e];
        const int pos = atomicAdd(&cur[r], 1);   // LDS atomic, returns old
        bsrc[pos] = edge_index[e];
        bdst[pos] = edge_index[N_EDGES_C + e];
    }
}

// One block per relation. Waves 0-3 accumulate head (src) quarters, waves 4-7
// tail (dst). 64 edge indices loaded per wave in ONE coalesced load and
// shfl-broadcast; row gathers issue 8-deep. After the LDS tree reduce the
// same block computes means -> t_c1 projection -> rin row [256] -> s_r1
// projection -> xt row [128] (= x_res2_rel = x_type for nonempty segments).
__global__ __launch_bounds__(512)
void k_accum(const float* __restrict__ x_e,
             const int* __restrict__ bsrc, const int* __restrict__ bdst,
             const int* __restrict__ startc, const int* __restrict__ cnt,
             const float* __restrict__ W_tc1, const float* __restrict__ b_tc1,
             const float* __restrict__ W_sr1, const float* __restrict__ b_sr1,
             float* __restrict__ rin_t,   // [NUM_REL][256]
             float* __restrict__ xt_t)    // [NUM_REL][128]
{
    __shared__ float red[8][E_HID_C];           // 8 KiB
    __shared__ float mh[E_HID_C], mt[E_HID_C], rin[E_HID_C];
    const int r    = blockIdx.x;
    const int tid  = threadIdx.x;
    const int w    = tid >> 6;
    const int lane = tid & 63;
    const int which = w >> 2;               // 0 = head, 1 = tail
    const int q     = w & 3;                // edge quarter
    const int base = startc[r];
    const int c    = cnt[r];
    const int qlen = (c + 3) >> 2;
    const int lo = base + q * qlen;
    const int hi = min(base + c, lo + qlen);
    const int* __restrict__ bn = which ? bdst : bsrc;

    float4 a = make_float4(0.f, 0.f, 0.f, 0.f);
    for (int g = lo; g < hi; g += 64) {
        const int m = min(64, hi - g);
        const int myidx = (g + lane < hi) ? bn[g + lane] : 0;
        int k = 0;
        for (; k + 8 <= m; k += 8) {
            float4 v[8];
#pragma unroll
            for (int u = 0; u < 8; ++u) {
                const int n = __shfl(myidx, k + u);
                v[u] = ((const float4*)(x_e + (size_t)n * E_HID_C))[lane];
            }
#pragma unroll
            for (int u = 0; u < 8; ++u) {
                a.x += v[u].x; a.y += v[u].y; a.z += v[u].z; a.w += v[u].w;
            }
        }
        for (; k < m; ++k) {
            const int n = __shfl(myidx, k);
            const float4 v = ((const float4*)(x_e + (size_t)n * E_HID_C))[lane];
            a.x += v.x; a.y += v.y; a.z += v.z; a.w += v.w;
        }
    }

    ((float4*)&red[w][0])[lane] = a;
    __syncthreads();

    // means (all 512 threads: wh = head/tail, d = feature)
    {
        const float inv = 1.0f / (float)(c > 0 ? c : 1);
        const int wh = tid >> 8;
        const int d  = tid & 255;
        const float s = red[wh * 4 + 0][d] + red[wh * 4 + 1][d] +
                        red[wh * 4 + 2][d] + red[wh * 4 + 3][d];
        (wh ? mt : mh)[d] = s * inv;
    }
    __syncthreads();

    // t_c1 projection: threads 0..127 -> mean_h @ W_tc1, 128..255 -> mean_t
    if (tid < 256) {
        const int j = tid & 127;
        const float* __restrict__ src = (tid < 128) ? mh : mt;
        float acc = b_tc1[j];
        for (int k = 0; k < E_HID_C; ++k)
            acc += src[k] * W_tc1[k * 128 + j];
        rin[(tid < 128 ? 0 : 128) + j] = acc;   // concat(mean_h, mean_t)
    }
    __syncthreads();

    if (tid < 256) {
        rin_t[(size_t)r * E_HID_C + tid] = rin[tid];
    } else if (tid < 384) {
        const int d = tid - 256;
        float acc = b_sr1[d];
        for (int k = 0; k < E_HID_C; ++k)
            acc += rin[k] * W_sr1[k * 128 + d];
        xt_t[(size_t)r * 128 + d] = acc;
    }
}

// out[e] = [ x_res1[e] + xt[rel[e]] | rin[rel[e]] ]. 8 edges per block; each
// 32-lane group owns one edge: 4 float4 loads + 3 float4 stores per thread,
// no integer division.
__global__ __launch_bounds__(256)
void k_out(const float* __restrict__ x_res1,
           const int* __restrict__ rel,
           const float* __restrict__ rin_t,
           const float* __restrict__ xt_t,
           float4* __restrict__ out)
{
    const float4* __restrict__ xr4  = (const float4*)x_res1;
    const float4* __restrict__ rin4 = (const float4*)rin_t;
    const float4* __restrict__ xt4  = (const float4*)xt_t;
    const int tid = threadIdx.x;
    const unsigned jj = tid & 31;
    const unsigned e  = blockIdx.x * 8u + (tid >> 5);
    const int r = rel[e];
    const float4 a = xr4[(size_t)e * 32 + jj];
    const float4 t = xt4[(size_t)r * 32 + jj];
    float4 o;
    o.x = a.x + t.x; o.y = a.y + t.y; o.z = a.z + t.z; o.w = a.w + t.w;
    float4* __restrict__ dst = out + (size_t)e * 96;
    dst[jj]      = o;
    dst[32 + jj] = rin4[(size_t)r * 64 + jj];
    dst[64 + jj] = rin4[(size_t)r * 64 + 32 + jj];
}

// ---------------------------------------------------------------------------
extern "C" void kernel_launch(void* const* d_in, const int* in_sizes, int n_in,
                              void* d_out, int out_size, void* d_ws, size_t ws_size,
                              hipStream_t stream)
{
    const float* x_e    = (const float*)d_in[0];
    const float* x_res1 = (const float*)d_in[1];
    const float* W_tc1  = (const float*)d_in[2];
    const float* b_tc1  = (const float*)d_in[3];
    const float* W_sr1  = (const float*)d_in[4];
    const float* b_sr1  = (const float*)d_in[5];
    // d_in[6]=a1, d_in[7]=a5 unused: scatter-softmax cancels (sum alpha = 1).
    const int* edge_index = (const int*)d_in[8];
    const int* rel        = (const int*)d_in[9];
    // d_in[10] = rel_size = arange(E): identity gather, unused.

    char* ws = (char*)d_ws;
    int*   part   = (int*)  (ws);                  // 125*1024*4 = 512,000 B
    int*   pbase  = (int*)  (ws + 512000);         // 512,000 B
    int*   cnt    = (int*)  (ws + 1024000);        // 4,096 B
    int*   startc = (int*)  (ws + 1028096);        // 4,096 B
    int*   bsrc   = (int*)  (ws + 1032192);        // 2,000,000 B
    int*   bdst   = (int*)  (ws + 3032192);        // 2,000,000 B
    float* rin_t  = (float*)(ws + 5032192);        // 1,024,000 B
    float* xt_t   = (float*)(ws + 6056192);        // 512,000 B
    // total ws use: 6,568,192 B

    k_zero   <<<1, RPAD, 0, stream>>>(cnt);
    k_hist   <<<NB_SORT, 1024, 0, stream>>>(rel, part, cnt);
    k_scan   <<<1, RPAD, 0, stream>>>(cnt, startc);
    k_pbase  <<<RPAD / 64, 64, 0, stream>>>(part, startc, pbase);
    k_scatter<<<NB_SORT, 1024, 0, stream>>>(edge_index, rel, pbase, bsrc, bdst);
    k_accum  <<<NUM_REL_C, 512, 0, stream>>>(x_e, bsrc, bdst, startc, cnt,
                                             W_tc1, b_tc1, W_sr1, b_sr1,
                                             rin_t, xt_t);
    k_out    <<<N_EDGES_C / 8, 256, 0, stream>>>(x_res1, rel, rin_t, xt_t,
                                                 (float4*)d_out);
}

// Round 5
// 318.361 us; speedup vs baseline: 5.1386x; 1.1991x over previous
//
#include <hip/hip_runtime.h>

// Problem constants (match reference)
#define N_NODES_C 100000
#define N_EDGES_C 500000
#define NUM_REL_C 1000
#define E_HID_C   256
#define RPAD      1024   // padded relation count (power of 2 for the scan)

#define NB_SORT   125    // sort blocks; 500000/125 = 4000 edges per block
#define CHUNK_E   (N_EDGES_C / NB_SORT)
#define NB_HIST   250    // k_hist grid when also converting x_e -> bf16
#define XE_F4     (N_NODES_C * E_HID_C / 4)     // 6,400,000 float4
#define CONV_PER_BLK (XE_F4 / NB_HIST)          // 25,600 float4 per block

// ---------------------------------------------------------------------------
// Algebra (validated R1-R4): scatter-softmax cancels (sum of alpha over each
// segment is 1 -> x_type[r] = x_res2_rel[r]); t_c1 is linear so it commutes
// with the per-rel mean. Only per-rel means of raw x_e rows are needed.
//
// Pipeline:
//   k_zero    : cnt[] = 0
//   k_hist    : per-block LDS histograms -> part[b][r]; atomic cnt[r];
//               blocks also convert x_e -> bf16 table (RNE) for cheap gathers
//   k_scan    : exclusive prefix sum cnt -> startc
//   k_pbase   : per-block bases pbase[b][r]
//   k_scatter : bucket (src,dst) int2 by relation via LDS cursors
//   k_accum   : per-rel register-accumulated segment sums (16-deep bf16
//               gathers) fused with means + both projections -> rin_t, xt_t
//   k_out     : streaming output assembly; NT loads/stores so the 1 GB
//               stream does not evict x_e / bf16 table from L3 across replays
// ---------------------------------------------------------------------------

typedef float f4 __attribute__((ext_vector_type(4)));

__device__ __forceinline__ unsigned short bf16rne(float f) {
    unsigned u = __float_as_uint(f);
    u += 0x7FFFu + ((u >> 16) & 1u);
    return (unsigned short)(u >> 16);
}

__global__ __launch_bounds__(1024)
void k_zero(int* __restrict__ cnt) {
    cnt[threadIdx.x] = 0;
}

__global__ __launch_bounds__(1024)
void k_hist(const int* __restrict__ rel, const float4* __restrict__ xe4,
            int* __restrict__ part, int* __restrict__ cnt,
            ushort4* __restrict__ xb4, const int do_conv) {
    __shared__ int h[RPAD];
    const int b = blockIdx.x, tid = threadIdx.x;
    const bool hist = (b < NB_SORT);
    if (hist) {
        h[tid] = 0;
        __syncthreads();
        const int base = b * CHUNK_E;
        for (int e = base + tid; e < base + CHUNK_E; e += 1024)
            atomicAdd(&h[rel[e]], 1);
    }
    if (do_conv) {
        const int cb = b * CONV_PER_BLK;
        for (int i = cb + tid; i < cb + CONV_PER_BLK; i += 1024) {
            const float4 v = xe4[i];
            ushort4 o;
            o.x = bf16rne(v.x); o.y = bf16rne(v.y);
            o.z = bf16rne(v.z); o.w = bf16rne(v.w);
            xb4[i] = o;
        }
    }
    if (hist) {
        __syncthreads();
        const int c = h[tid];
        part[b * RPAD + tid] = c;
        if (c) atomicAdd(&cnt[tid], c);
    }
}

__global__ __launch_bounds__(1024)
void k_scan(const int* __restrict__ cnt, int* __restrict__ startc) {
    __shared__ int s[2][RPAD];
    const int t = threadIdx.x;
    const int v = cnt[t];
    s[0][t] = v;
    __syncthreads();
    int cur = 0;
    for (int off = 1; off < RPAD; off <<= 1) {
        const int add = (t >= off) ? s[cur][t - off] : 0;
        s[cur ^ 1][t] = s[cur][t] + add;
        cur ^= 1;
        __syncthreads();
    }
    startc[t] = s[cur][t] - v;
}

__global__ __launch_bounds__(64)
void k_pbase(const int* __restrict__ part, const int* __restrict__ startc,
             int* __restrict__ pbase) {
    const int r = blockIdx.x * 64 + threadIdx.x;   // r < RPAD
    int run = startc[r];
#pragma unroll 5
    for (int b = 0; b < NB_SORT; ++b) {
        pbase[b * RPAD + r] = run;
        run += part[b * RPAD + r];
    }
}

__global__ __launch_bounds__(1024)
void k_scatter(const int* __restrict__ edge_index, const int* __restrict__ rel,
               const int* __restrict__ pbase, int2* __restrict__ bpair) {
    __shared__ int cur[RPAD];
    const int b = blockIdx.x, tid = threadIdx.x;
    cur[tid] = pbase[b * RPAD + tid];
    __syncthreads();
    const int base = b * CHUNK_E;
    for (int e = base + tid; e < base + CHUNK_E; e += 1024) {
        const int r = rel[e];
        const int pos = atomicAdd(&cur[r], 1);   // LDS atomic, returns old
        bpair[pos] = make_int2(edge_index[e], edge_index[N_EDGES_C + e]);
    }
}

// One block per relation. Waves 0-3 accumulate head (src) quarters, waves 4-7
// tail (dst). 64 edge pairs loaded per wave in ONE coalesced int2 load and
// shfl-broadcast; row gathers issue 16-deep (bf16) / 8-deep (f32 fallback).
// Epilogue: means -> t_c1 projection -> rin row [256] -> s_r1 projection ->
// xt row [128] (= x_res2_rel = x_type for nonempty segments).
template<bool BF16>
__global__ __launch_bounds__(512)
void k_accum(const float* __restrict__ x_e, const unsigned short* __restrict__ xb,
             const int2* __restrict__ bp,
             const int* __restrict__ startc, const int* __restrict__ cnt,
             const float* __restrict__ W_tc1, const float* __restrict__ b_tc1,
             const float* __restrict__ W_sr1, const float* __restrict__ b_sr1,
             float* __restrict__ rin_t,   // [NUM_REL][256]
             float* __restrict__ xt_t)    // [NUM_REL][128]
{
    __shared__ float red[8][E_HID_C];           // 8 KiB
    __shared__ float mh[E_HID_C], mt[E_HID_C], rin[E_HID_C];
    const int r    = blockIdx.x;
    const int tid  = threadIdx.x;
    const int w    = tid >> 6;
    const int lane = tid & 63;
    const int which = w >> 2;               // 0 = head, 1 = tail
    const int q     = w & 3;                // edge quarter
    const int base = startc[r];
    const int c    = cnt[r];
    const int qlen = (c + 3) >> 2;
    const int lo = base + q * qlen;
    const int hi = min(base + c, lo + qlen);

    float4 a = make_float4(0.f, 0.f, 0.f, 0.f);
    for (int g = lo; g < hi; g += 64) {
        const int m = min(64, hi - g);
        int2 pr = make_int2(0, 0);
        if (g + lane < hi) pr = bp[g + lane];
        const int myidx = which ? pr.y : pr.x;
        int k = 0;
        if (BF16) {
            for (; k + 16 <= m; k += 16) {
                uint2 v[16];
#pragma unroll
                for (int u = 0; u < 16; ++u) {
                    const int n = __shfl(myidx, k + u);
                    v[u] = ((const uint2*)(xb + (size_t)n * E_HID_C))[lane];
                }
#pragma unroll
                for (int u = 0; u < 16; ++u) {
                    a.x += __uint_as_float(v[u].x << 16);
                    a.y += __uint_as_float(v[u].x & 0xFFFF0000u);
                    a.z += __uint_as_float(v[u].y << 16);
                    a.w += __uint_as_float(v[u].y & 0xFFFF0000u);
                }
            }
            for (; k < m; ++k) {
                const int n = __shfl(myidx, k);
                const uint2 v = ((const uint2*)(xb + (size_t)n * E_HID_C))[lane];
                a.x += __uint_as_float(v.x << 16);
                a.y += __uint_as_float(v.x & 0xFFFF0000u);
                a.z += __uint_as_float(v.y << 16);
                a.w += __uint_as_float(v.y & 0xFFFF0000u);
            }
        } else {
            for (; k + 8 <= m; k += 8) {
                float4 v[8];
#pragma unroll
                for (int u = 0; u < 8; ++u) {
                    const int n = __shfl(myidx, k + u);
                    v[u] = ((const float4*)(x_e + (size_t)n * E_HID_C))[lane];
                }
#pragma unroll
                for (int u = 0; u < 8; ++u) {
                    a.x += v[u].x; a.y += v[u].y; a.z += v[u].z; a.w += v[u].w;
                }
            }
            for (; k < m; ++k) {
                const int n = __shfl(myidx, k);
                const float4 v = ((const float4*)(x_e + (size_t)n * E_HID_C))[lane];
                a.x += v.x; a.y += v.y; a.z += v.z; a.w += v.w;
            }
        }
    }

    ((float4*)&red[w][0])[lane] = a;
    __syncthreads();

    // means (all 512 threads: wh = head/tail, d = feature)
    {
        const float inv = 1.0f / (float)(c > 0 ? c : 1);
        const int wh = tid >> 8;
        const int d  = tid & 255;
        const float s = red[wh * 4 + 0][d] + red[wh * 4 + 1][d] +
                        red[wh * 4 + 2][d] + red[wh * 4 + 3][d];
        (wh ? mt : mh)[d] = s * inv;
    }
    __syncthreads();

    // t_c1 projection: threads 0..127 -> mean_h @ W_tc1, 128..255 -> mean_t
    if (tid < 256) {
        const int j = tid & 127;
        const float* __restrict__ src = (tid < 128) ? mh : mt;
        float acc = b_tc1[j];
        for (int k = 0; k < E_HID_C; ++k)
            acc += src[k] * W_tc1[k * 128 + j];
        rin[(tid < 128 ? 0 : 128) + j] = acc;   // concat(mean_h, mean_t)
    }
    __syncthreads();

    if (tid < 256) {
        rin_t[(size_t)r * E_HID_C + tid] = rin[tid];
    } else if (tid < 384) {
        const int d = tid - 256;
        float acc = b_sr1[d];
        for (int k = 0; k < E_HID_C; ++k)
            acc += rin[k] * W_sr1[k * 128 + d];
        xt_t[(size_t)r * 128 + d] = acc;
    }
}

// out[e] = [ x_res1[e] + xt[rel[e]] | rin[rel[e]] ]. 8 edges per block; each
// 32-lane group owns one edge. NT load for x_res1 (zero reuse) and NT stores
// for out (streams past L2/L3, keeping x_e / bf16 table resident).
__global__ __launch_bounds__(256)
void k_out(const float* __restrict__ x_res1,
           const int* __restrict__ rel,
           const float* __restrict__ rin_t,
           const float* __restrict__ xt_t,
           float* __restrict__ out)
{
    const f4* __restrict__ xr4  = (const f4*)x_res1;
    const f4* __restrict__ rin4 = (const f4*)rin_t;
    const f4* __restrict__ xt4  = (const f4*)xt_t;
    f4* __restrict__ o4 = (f4*)out;
    const int tid = threadIdx.x;
    const unsigned jj = tid & 31;
    const unsigned e  = blockIdx.x * 8u + (tid >> 5);
    const int r = rel[e];
    const f4 a = __builtin_nontemporal_load(&xr4[(size_t)e * 32 + jj]);
    const f4 t = xt4[(size_t)r * 32 + jj];
    f4* __restrict__ dst = o4 + (size_t)e * 96;
    __builtin_nontemporal_store(a + t, &dst[jj]);
    __builtin_nontemporal_store(rin4[(size_t)r * 64 + jj],      &dst[32 + jj]);
    __builtin_nontemporal_store(rin4[(size_t)r * 64 + 32 + jj], &dst[64 + jj]);
}

// ---------------------------------------------------------------------------
extern "C" void kernel_launch(void* const* d_in, const int* in_sizes, int n_in,
                              void* d_out, int out_size, void* d_ws, size_t ws_size,
                              hipStream_t stream)
{
    const float* x_e    = (const float*)d_in[0];
    const float* x_res1 = (const float*)d_in[1];
    const float* W_tc1  = (const float*)d_in[2];
    const float* b_tc1  = (const float*)d_in[3];
    const float* W_sr1  = (const float*)d_in[4];
    const float* b_sr1  = (const float*)d_in[5];
    // d_in[6]=a1, d_in[7]=a5 unused: scatter-softmax cancels (sum alpha = 1).
    const int* edge_index = (const int*)d_in[8];
    const int* rel        = (const int*)d_in[9];
    // d_in[10] = rel_size = arange(E): identity gather, unused.

    char* ws = (char*)d_ws;
    int*   part   = (int*)  (ws);                  // 125*1024*4 = 512,000 B
    int*   pbase  = (int*)  (ws + 512000);         // 512,000 B
    int*   cnt    = (int*)  (ws + 1024000);        // 4,096 B
    int*   startc = (int*)  (ws + 1028096);        // 4,096 B
    int2*  bpair  = (int2*) (ws + 1032192);        // 4,000,000 B
    float* rin_t  = (float*)(ws + 5032192);        // 1,024,000 B
    float* xt_t   = (float*)(ws + 6056192);        // 512,000 B
    unsigned short* xb = (unsigned short*)(ws + 6568192);  // 51,200,000 B
    const size_t need_bf16 = 6568192ull + 51200000ull;     // 57,768,192 B
    const bool use_bf16 = (ws_size >= need_bf16);

    k_zero   <<<1, RPAD, 0, stream>>>(cnt);
    k_hist   <<<use_bf16 ? NB_HIST : NB_SORT, 1024, 0, stream>>>(
                 rel, (const float4*)x_e, part, cnt,
                 (ushort4*)xb, use_bf16 ? 1 : 0);
    k_scan   <<<1, RPAD, 0, stream>>>(cnt, startc);
    k_pbase  <<<RPAD / 64, 64, 0, stream>>>(part, startc, pbase);
    k_scatter<<<NB_SORT, 1024, 0, stream>>>(edge_index, rel, pbase, bpair);
    if (use_bf16) {
        k_accum<true><<<NUM_REL_C, 512, 0, stream>>>(
            x_e, xb, bpair, startc, cnt,
            W_tc1, b_tc1, W_sr1, b_sr1, rin_t, xt_t);
    } else {
        k_accum<false><<<NUM_REL_C, 512, 0, stream>>>(
            x_e, xb, bpair, startc, cnt,
            W_tc1, b_tc1, W_sr1, b_sr1, rin_t, xt_t);
    }
    k_out    <<<N_EDGES_C / 8, 256, 0, stream>>>(x_res1, rel, rin_t, xt_t,
                                                 (float*)d_out);
}